// Round 3
// baseline (362.928 us; speedup 1.0000x reference)
//
#include <hip/hip_runtime.h>
#include <stdint.h>
#include <math.h>

// pred_out [8,5,768,768] f32, target_mask [8,1,768,768] i32 (0..3), num_target_classes=4.
#define B_ 8
#define C_ 5
#define H_ 768
#define W_ 768
#define HW_ (H_*W_)
#define HWq (HW_/4)            // float4 per plane
#define Wq (W_/4)              // 192
#define NPIX (B_*HW_)          // 4,718,592
#define TB 8
#define INVAL 0xFFFFFFFFu
#define FIX 16777216.0
#define LN2F 0.69314718056f
#define TILE 64
#define TPR 12
#define TPC 12
#define NTILES (B_*TPR*TPC)    // 1152
#define SEAMS_PER_IMG (11*768)
#define NB_HALF (B_*SEAMS_PER_IMG)   // 67584
#define NB_TOT (2*NB_HALF)           // 135168

struct Acc {
  long long f_logpc[TB][C_];
  long long f_log1m[TB][C_];
  long long f_pred [TB][C_];
  unsigned  cnt[TB][C_];
  unsigned  ncomp[8];          // local roots added by k_main, merges subtracted by k_seam
};

// ---------------- global union-find (lock-free, agent scope) ----------------
static __device__ __forceinline__ unsigned pload(const unsigned* P, unsigned i) {
  return __hip_atomic_load(&P[i], __ATOMIC_RELAXED, __HIP_MEMORY_SCOPE_AGENT);
}
static __device__ unsigned findRootG(unsigned* P, unsigned i) {
  unsigned p = pload(P, i);
  if (p == i) return i;
  unsigned gp = pload(P, p);
  while (p != gp) {
    __hip_atomic_store(&P[i], gp, __ATOMIC_RELAXED, __HIP_MEMORY_SCOPE_AGENT);
    i = p; p = gp; gp = pload(P, p);
  }
  return p;
}
// returns true iff this call performed a link (merged two distinct components)
static __device__ bool uniteG(unsigned* P, unsigned a, unsigned b) {
  a = findRootG(P, a);
  b = findRootG(P, b);
  while (a != b) {
    if (a < b) { unsigned t = a; a = b; b = t; }   // link larger -> smaller
    unsigned old = atomicCAS(&P[a], a, b);
    if (old == a) return true;                     // a was root, now linked: one real merge
    a = findRootG(P, old);
    b = findRootG(P, b);
  }
  return false;
}
// ---------------- LDS union-find (workgroup scope) ----------------
static __device__ __forceinline__ unsigned ploadL(const unsigned* P, unsigned i) {
  return __hip_atomic_load(&P[i], __ATOMIC_RELAXED, __HIP_MEMORY_SCOPE_WORKGROUP);
}
static __device__ unsigned findRootL(const unsigned* P, unsigned i) {
  unsigned p = ploadL(P, i);
  while (p != i) { i = p; p = ploadL(P, i); }
  return i;
}
static __device__ void uniteL(unsigned* P, unsigned a, unsigned b) {
  a = findRootL(P, a);
  b = findRootL(P, b);
  while (a != b) {
    if (a < b) { unsigned t = a; a = b; b = t; }
    unsigned old = atomicCAS(&P[a], a, b);
    if (old == a) return;
    a = findRootL(P, old);
    b = findRootL(P, b);
  }
}

// ---------------- kernels ----------------
__global__ void k_zero(Acc* acc) {
  unsigned* p = (unsigned*)acc;
  int n = (int)(sizeof(Acc) / sizeof(unsigned));
  for (int i = threadIdx.x; i < n; i += blockDim.x) p[i] = 0u;
}

// Fused: argmax + stats + tile-local CCL + root count + edge/root emission.
// One block per 64x64 tile.
__global__ __launch_bounds__(256) void k_main(
    const float4* __restrict__ pred4, const int4* __restrict__ tgt4,
    unsigned char* __restrict__ clsg, unsigned* __restrict__ parent,
    Acc* __restrict__ acc)
{
  __shared__ unsigned lab[TILE*TILE];        // 16 KB
  __shared__ unsigned lclsw[TILE*TILE/4];    // 4 KB (bytes)
  __shared__ float s_logpc[4][TB*C_];
  __shared__ float s_log1m[4][TB*C_];
  __shared__ float s_pred[4][TB*C_];
  __shared__ unsigned s_cnt[4][TB*C_];
  __shared__ unsigned s_rt[4];
  unsigned char* lcls = (unsigned char*)lclsw;

  for (int i = threadIdx.x; i < 4*TB*C_; i += blockDim.x) {
    (&s_logpc[0][0])[i] = 0.f; (&s_log1m[0][0])[i] = 0.f;
    (&s_pred[0][0])[i] = 0.f;  (&s_cnt[0][0])[i] = 0u;
  }
  if (threadIdx.x < 4) s_rt[threadIdx.x] = 0u;
  __syncthreads();

  int blk = blockIdx.x;
  int b = blk / (TPR*TPC);
  int rem = blk - b * (TPR*TPC);
  int ty0 = (rem / TPR) * TILE;
  int tx0 = (rem - (rem / TPR) * TPR) * TILE;
  const int w = threadIdx.x >> 6;

  // ---- phase 1: load pred/tgt, argmax, stats, init lab/cls in LDS ----
#pragma unroll
  for (int it = 0; it < 4; ++it) {
    int li4 = threadIdx.x + it * 256;       // float4-group id in tile (0..1023)
    int ty = li4 >> 4;                      // 16 groups per 64-px row
    int txq = li4 & 15;
    int g0 = ((b * C_) * H_ + (ty0 + ty)) * Wq + (tx0 >> 2) + txq;
    float4 p0 = pred4[g0];
    float4 p1 = pred4[g0 + HWq];
    float4 p2 = pred4[g0 + 2*HWq];
    float4 p3 = pred4[g0 + 3*HWq];
    float4 p4 = pred4[g0 + 4*HWq];
    int4 t4 = tgt4[(b * H_ + ty0 + ty) * Wq + (tx0 >> 2) + txq];
    unsigned packed = 0;
    uint4 labw;
    unsigned pibase = (unsigned)(li4 * 4);
#define DOPIX(J, V0, V1, V2, V3, V4, T, LW)                                    \
    {                                                                          \
      float best = (V0); int bc = 0;                                           \
      if ((V1) > best) { best = (V1); bc = 1; }                                \
      if ((V2) > best) { best = (V2); bc = 2; }                                \
      if ((V3) > best) { best = (V3); bc = 3; }                                \
      if ((V4) > best) { best = (V4); bc = 4; }                                \
      unsigned tt = (unsigned)(T); if (tt >= TB) tt = TB - 1;                  \
      int slot = (int)tt * C_ + bc;                                            \
      atomicAdd(&s_cnt[w][slot], 1u);                                          \
      if (bc) {                                                                \
        float pc = fminf(fmaxf(best, 1e-7f), 1.0f - 1e-7f);                    \
        atomicAdd(&s_pred[w][slot], best);                                     \
        atomicAdd(&s_logpc[w][slot], __log2f(pc) * LN2F);                      \
        atomicAdd(&s_log1m[w][slot], __log2f(1.0f - pc) * LN2F);               \
      }                                                                        \
      packed |= ((unsigned)bc) << (8 * (J));                                   \
      (LW) = bc ? (pibase + (J)) : INVAL;                                      \
    }
    DOPIX(0, p0.x, p1.x, p2.x, p3.x, p4.x, t4.x, labw.x)
    DOPIX(1, p0.y, p1.y, p2.y, p3.y, p4.y, t4.y, labw.y)
    DOPIX(2, p0.z, p1.z, p2.z, p3.z, p4.z, t4.z, labw.z)
    DOPIX(3, p0.w, p1.w, p2.w, p3.w, p4.w, t4.w, labw.w)
#undef DOPIX
    lclsw[li4] = packed;
    *(uint4*)&lab[li4 * 4] = labw;
  }
  __syncthreads();

  // ---- phase 2: tile-local union-find (right + down edges) ----
#pragma unroll
  for (int it = 0; it < 16; ++it) {
    int li = threadIdx.x + it * 256;
    unsigned char c = lcls[li];
    if (!c) continue;
    int tx = li & 63, ty = li >> 6;
    if (tx < 63 && lcls[li + 1] == c)  uniteL(lab, li, li + 1);
    if (ty < 63 && lcls[li + 64] == c) uniteL(lab, li, li + 64);
  }
  __syncthreads();

  // ---- phase 3: count local roots; emit parent (roots+edges) and edge cls ----
#pragma unroll
  for (int it = 0; it < 16; ++it) {
    int li = threadIdx.x + it * 256;
    int tx = li & 63, ty = li >> 6;
    bool edge = (tx == 0) | (tx == 63) | (ty == 0) | (ty == 63);
    unsigned char c = lcls[li];
    unsigned g = (unsigned)(b * HW_ + (ty0 + ty) * W_ + tx0 + tx);
    if (edge) clsg[g] = c;                 // bg too: seam kernel must not read poison
    if (!c) continue;
    bool isRoot = (lab[li] == (unsigned)li);
    if (isRoot) atomicAdd(&s_rt[c - 1], 1u);
    if (isRoot | edge) {
      unsigned r = findRootL(lab, (unsigned)li);
      unsigned gr = (unsigned)(b * HW_ + (ty0 + (int)(r >> 6)) * W_ + tx0 + (int)(r & 63));
      parent[g] = gr;
    }
  }
  __syncthreads();

  // ---- flush block partials ----
  for (int i = threadIdx.x; i < TB*C_; i += blockDim.x) {
    unsigned c = s_cnt[0][i] + s_cnt[1][i] + s_cnt[2][i] + s_cnt[3][i];
    if (c) atomicAdd(&(&acc->cnt[0][0])[i], c);
    double vp = (double)s_pred[0][i] + s_pred[1][i] + s_pred[2][i] + s_pred[3][i];
    double vl = (double)s_logpc[0][i] + s_logpc[1][i] + s_logpc[2][i] + s_logpc[3][i];
    double vm = (double)s_log1m[0][i] + s_log1m[1][i] + s_log1m[2][i] + s_log1m[3][i];
    if (vp != 0.0)
      atomicAdd((unsigned long long*)&(&acc->f_pred[0][0])[i],
                (unsigned long long)(long long)llrint(vp * FIX));
    if (vl != 0.0)
      atomicAdd((unsigned long long*)&(&acc->f_logpc[0][0])[i],
                (unsigned long long)(long long)llrint(vl * FIX));
    if (vm != 0.0)
      atomicAdd((unsigned long long*)&(&acc->f_log1m[0][0])[i],
                (unsigned long long)(long long)llrint(vm * FIX));
  }
  if (threadIdx.x < 4 && s_rt[threadIdx.x])
    atomicAdd(&acc->ncomp[threadIdx.x], s_rt[threadIdx.x]);
}

// Merge across tile seams; every successful link removes exactly one component.
__global__ __launch_bounds__(256) void k_seam(const unsigned char* __restrict__ clsg,
                                              unsigned* __restrict__ parent,
                                              Acc* __restrict__ acc)
{
  int idx = blockIdx.x * blockDim.x + threadIdx.x;
  if (idx >= NB_TOT) return;
  unsigned p, q;
  if (idx < NB_HALF) {             // down edges across seam rows h = r*64+63
    int b = idx / SEAMS_PER_IMG;
    int r2 = idx - b * SEAMS_PER_IMG;
    int rrow = r2 / W_;
    int col = r2 - rrow * W_;
    int h = rrow * TILE + (TILE - 1);
    p = (unsigned)(b * HW_ + h * W_ + col);
    q = p + W_;
  } else {                         // right edges across seam cols w = r*64+63
    int i2 = idx - NB_HALF;
    int b = i2 / SEAMS_PER_IMG;
    int r2 = i2 - b * SEAMS_PER_IMG;
    int rcol = r2 / H_;
    int row = r2 - rcol * H_;
    int ww = rcol * TILE + (TILE - 1);
    p = (unsigned)(b * HW_ + row * W_ + ww);
    q = p + 1;
  }
  unsigned char c = clsg[p];
  if (c && clsg[q] == c) {
    if (uniteG(parent, p, q)) atomicSub(&acc->ncomp[c - 1], 1u);
  }
}

__global__ void k_final(const Acc* __restrict__ acc, const int* __restrict__ ntcp,
                        float* __restrict__ out)
{
  if (threadIdx.x || blockIdx.x) return;
  int NT = ntcp[0];
  if (NT < 1) NT = 1;
  if (NT > TB) NT = TB;

  double logpc[TB][C_], log1m[TB][C_], spred[TB][C_], cnt[TB][C_];
  unsigned cnti[TB][C_];
  for (int t = 0; t < TB; ++t)
    for (int c = 0; c < C_; ++c) {
      cnti[t][c]  = acc->cnt[t][c];
      cnt[t][c]   = (double)cnti[t][c];
      logpc[t][c] = (double)acc->f_logpc[t][c] / FIX;
      log1m[t][c] = (double)acc->f_log1m[t][c] / FIX;
      spred[t][c] = (double)acc->f_pred[t][c] / FIX;
    }
  unsigned ctot[C_];
  for (int c = 0; c < C_; ++c) {
    unsigned s = 0;
    for (int t = 0; t < TB; ++t) s += cnti[t][c];
    ctot[c] = s;
  }
  unsigned ncomp[C_] = {0, 0, 0, 0, 0};
  for (int v = 1; v < C_; ++v) ncomp[v] = acc->ncomp[v - 1];

  // ph per predicted class: exact f32 replay incl. int32 wrap of n_comp*last_i
  float ph_tab[C_];
  for (int cc = 0; cc < C_; ++cc) {
    float ph = 0.0f;
    int li = 1;
    for (int v = 1; v < C_; ++v) {
      if (ctot[v] > 0) {
        int prod = (int)((unsigned)ncomp[v] * (unsigned)li);
        float sv = (float)prod;
        float inc = ((cc == v) ? 1.0f : 0.0f) + sv;
        ph = ph + inc;
        li = li + (int)ncomp[v] + ((ctot[v] < (unsigned)NPIX) ? 1 : 0);
      }
    }
    ph_tab[cc] = ph;
  }

  const float EPSF = 1e-7f;
  const double L1 = (double)logf(1.0f - EPSF);
  const double M1 = (double)log1pf(-(1.0f - EPSF));
  const double L0 = (double)logf(EPSF);
  const double M0 = (double)log1pf(-EPSF);
  const double N = (double)NPIX;

  double nt0 = 0; for (int c = 0; c < C_; ++c) nt0 += cnt[0][c];
  double np1 = (double)ctot[0];
  double n11 = cnt[0][0];
  double res = -(n11*L1 + (nt0 - n11)*L0 + (np1 - n11)*M1 + (N - nt0 - np1 + n11)*M0) / N
               + 1.0 - (2.0*n11 + 1.0) / (np1 + nt0 + 1.0);

  for (int t = 1; t < NT; ++t) {
    double ntt = 0; long long ntti = 0;
    for (int c = 0; c < C_; ++c) { ntt += cnt[t][c]; ntti += (long long)cnti[t][c]; }
    if (ntti == 0) continue;
    int idx[C_] = {0, 1, 2, 3, 4};
    for (int i = 1; i < C_; ++i)
      for (int j = i; j > 0 && ph_tab[idx[j]] < ph_tab[idx[j-1]]; --j) {
        int tmp = idx[j]; idx[j] = idx[j-1]; idx[j-1] = tmp;
      }
    long long k = (ntti - 1) / 2;
    float med = ph_tab[idx[C_ - 1]];
    long long cum = 0;
    for (int i = 0; i < C_; ++i) {
      cum += (long long)cnti[t][idx[i]];
      if (cum > k) { med = ph_tab[idx[i]]; break; }
    }
    double A = 0, Bt = 0, inter = 0, sum_p = 0, ex = 0, nfg_t = 0, nfg_all = 0;
    for (int c = 1; c < C_; ++c) {
      if (ph_tab[c] == med) {
        A += logpc[t][c];
        inter += spred[t][c];
        nfg_t += cnt[t][c];
        for (int t2 = 0; t2 < TB; ++t2) {
          nfg_all += cnt[t2][c];
          sum_p += spred[t2][c];
          if (t2 != t) Bt += log1m[t2][c];
        }
      } else {
        ex += spred[t][c];
      }
    }
    double bce  = -(A + Bt + (ntt - nfg_t)*L0 + (N - ntt - (nfg_all - nfg_t))*M0) / N;
    double dice = 1.0 - (2.0*inter + 1.0) / (sum_p + ntt + 1.0);
    res += bce + dice + ex / ntt;
  }

  int nun = 0;
  for (int t = 0; t < NT; ++t) {
    long long s = 0;
    for (int c = 0; c < C_; ++c) s += (long long)cnti[t][c];
    if (s) nun++;
  }
  out[0] = (float)(res / (double)(2 * nun + 1));
}

extern "C" void kernel_launch(void* const* d_in, const int* in_sizes, int n_in,
                              void* d_out, int out_size, void* d_ws, size_t ws_size,
                              hipStream_t stream) {
  const float* pred = (const float*)d_in[0];
  const int* tgt = (const int*)d_in[1];
  const int* ntc = (const int*)d_in[2];
  float* out = (float*)d_out;
  char* ws = (char*)d_ws;
  // ws layout: parent u32[NPIX] | cls u8[NPIX] | Acc  (23.6 MB)
  unsigned* parent = (unsigned*)ws;
  unsigned char* cls = (unsigned char*)(ws + (size_t)NPIX * 4);
  Acc* acc = (Acc*)(ws + (size_t)NPIX * 5);

  hipLaunchKernelGGL(k_zero, dim3(1), dim3(256), 0, stream, acc);
  hipLaunchKernelGGL(k_main, dim3(NTILES), dim3(256), 0, stream,
                     (const float4*)pred, (const int4*)tgt, cls, parent, acc);
  hipLaunchKernelGGL(k_seam, dim3((NB_TOT + 255) / 256), dim3(256), 0, stream,
                     cls, parent, acc);
  hipLaunchKernelGGL(k_final, dim3(1), dim3(1), 0, stream, acc, ntc, out);
}

// Round 4
// 270.692 us; speedup vs baseline: 1.3407x; 1.3407x over previous
//
#include <hip/hip_runtime.h>
#include <stdint.h>
#include <math.h>

// pred_out [8,5,768,768] f32, target_mask [8,1,768,768] i32 (0..3), num_target_classes=4.
#define B_ 8
#define C_ 5
#define H_ 768
#define W_ 768
#define HW_ (H_*W_)
#define HWq (HW_/4)            // float4 per plane
#define Wq (W_/4)              // 192
#define NPIX (B_*HW_)          // 4,718,592
#define TB 8
#define INVAL 0xFFFFFFFFu
#define FIX 16777216.0
#define LN2F 0.69314718056f
#define TILE 64
#define TPR 12
#define TPC 12
#define NTILES (B_*TPR*TPC)    // 1152
#define NNODES (NTILES*256)    // 294912 node-UF entries (1.18 MB)
#define SEAMS_PER_IMG (11*768) // 8448
#define NB_HALF (B_*SEAMS_PER_IMG)   // 67584
#define NB_TOT (2*NB_HALF)           // 135168

struct Acc {
  long long f_logpc[TB][C_];
  long long f_log1m[TB][C_];
  long long f_pred [TB][C_];
  unsigned  cnt[TB][C_];
  unsigned  ncomp[8];          // local roots added by k_main, node-merges subtracted by k_seam
};

// ---------------- compact node union-find (lock-free, agent scope, L2-resident) ----------------
static __device__ __forceinline__ unsigned pload(const unsigned* P, unsigned i) {
  return __hip_atomic_load(&P[i], __ATOMIC_RELAXED, __HIP_MEMORY_SCOPE_AGENT);
}
static __device__ unsigned findRootG(unsigned* P, unsigned i) {
  unsigned p = pload(P, i);
  if (p == i) return i;
  unsigned gp = pload(P, p);
  while (p != gp) {
    __hip_atomic_store(&P[i], gp, __ATOMIC_RELAXED, __HIP_MEMORY_SCOPE_AGENT);  // path halving
    i = p; p = gp; gp = pload(P, p);
  }
  return p;
}
// true iff this call linked two distinct components (exactly one real merge)
static __device__ bool uniteG(unsigned* P, unsigned a, unsigned b) {
  a = findRootG(P, a);
  b = findRootG(P, b);
  while (a != b) {
    if (a < b) { unsigned t = a; a = b; b = t; }
    unsigned old = atomicCAS(&P[a], a, b);
    if (old == a) return true;
    a = findRootG(P, old);
    b = findRootG(P, b);
  }
  return false;
}
// ---------------- LDS union-find (workgroup scope) ----------------
static __device__ __forceinline__ unsigned ploadL(const unsigned* P, unsigned i) {
  return __hip_atomic_load(&P[i], __ATOMIC_RELAXED, __HIP_MEMORY_SCOPE_WORKGROUP);
}
static __device__ unsigned findRootL(const unsigned* P, unsigned i) {
  unsigned p = ploadL(P, i);
  while (p != i) { i = p; p = ploadL(P, i); }
  return i;
}
static __device__ void uniteL(unsigned* P, unsigned a, unsigned b) {
  a = findRootL(P, a);
  b = findRootL(P, b);
  while (a != b) {
    if (a < b) { unsigned t = a; a = b; b = t; }
    unsigned old = atomicCAS(&P[a], a, b);
    if (old == a) return;
    a = findRootL(P, old);
    b = findRootL(P, b);
  }
}

// ---------------- kernels ----------------
__global__ void k_zero(Acc* acc) {
  unsigned* p = (unsigned*)acc;
  int n = (int)(sizeof(Acc) / sizeof(unsigned));
  for (int i = threadIdx.x; i < n; i += blockDim.x) p[i] = 0u;
}

// Fused: argmax + stats + tile-local CCL + root count + compact border emission + P2 init.
// One block per 64x64 tile. No full-size global arrays written.
__global__ __launch_bounds__(256) void k_main(
    const float4* __restrict__ pred4, const int4* __restrict__ tgt4,
    unsigned short* __restrict__ border, unsigned* __restrict__ P2,
    Acc* __restrict__ acc)
{
  __shared__ unsigned lab[TILE*TILE];        // 16 KB
  __shared__ unsigned lclsw[TILE*TILE/4];    // 4 KB (bytes)
  __shared__ unsigned s_rootmin[TILE*TILE];  // 16 KB: local-root li -> min border idx
  __shared__ float s_logpc[4][TB*C_];
  __shared__ float s_log1m[4][TB*C_];
  __shared__ float s_pred[4][TB*C_];
  __shared__ unsigned s_cnt[4][TB*C_];
  __shared__ unsigned s_rt[4];
  unsigned char* lcls = (unsigned char*)lclsw;

  for (int i = threadIdx.x; i < 4*TB*C_; i += blockDim.x) {
    (&s_logpc[0][0])[i] = 0.f; (&s_log1m[0][0])[i] = 0.f;
    (&s_pred[0][0])[i] = 0.f;  (&s_cnt[0][0])[i] = 0u;
  }
#pragma unroll
  for (int it = 0; it < 16; ++it) s_rootmin[threadIdx.x + it * 256] = INVAL;
  if (threadIdx.x < 4) s_rt[threadIdx.x] = 0u;
  // init this tile's 256 node-UF entries (coalesced, once)
  {
    unsigned n = (unsigned)blockIdx.x * 256u + threadIdx.x;
    P2[n] = n;
  }
  __syncthreads();

  int blk = blockIdx.x;
  int b = blk / (TPR*TPC);
  int rem = blk - b * (TPR*TPC);
  int ty0 = (rem / TPR) * TILE;
  int tx0 = (rem - (rem / TPR) * TPR) * TILE;
  const int w = threadIdx.x >> 6;

  // ---- phase 1: load pred/tgt, argmax, stats, init lab/cls in LDS ----
#pragma unroll
  for (int it = 0; it < 4; ++it) {
    int li4 = threadIdx.x + it * 256;       // float4-group id in tile (0..1023)
    int ty = li4 >> 4;                      // 16 groups per 64-px row
    int txq = li4 & 15;
    int g0 = ((b * C_) * H_ + (ty0 + ty)) * Wq + (tx0 >> 2) + txq;
    float4 p0 = pred4[g0];
    float4 p1 = pred4[g0 + HWq];
    float4 p2 = pred4[g0 + 2*HWq];
    float4 p3 = pred4[g0 + 3*HWq];
    float4 p4 = pred4[g0 + 4*HWq];
    int4 t4 = tgt4[(b * H_ + ty0 + ty) * Wq + (tx0 >> 2) + txq];
    unsigned packed = 0;
    uint4 labw;
    unsigned pibase = (unsigned)(li4 * 4);
#define DOPIX(J, V0, V1, V2, V3, V4, T, LW)                                    \
    {                                                                          \
      float best = (V0); int bc = 0;                                           \
      if ((V1) > best) { best = (V1); bc = 1; }                                \
      if ((V2) > best) { best = (V2); bc = 2; }                                \
      if ((V3) > best) { best = (V3); bc = 3; }                                \
      if ((V4) > best) { best = (V4); bc = 4; }                                \
      unsigned tt = (unsigned)(T); if (tt >= TB) tt = TB - 1;                  \
      int slot = (int)tt * C_ + bc;                                            \
      atomicAdd(&s_cnt[w][slot], 1u);                                          \
      if (bc) {                                                                \
        float pc = fminf(fmaxf(best, 1e-7f), 1.0f - 1e-7f);                    \
        atomicAdd(&s_pred[w][slot], best);                                     \
        atomicAdd(&s_logpc[w][slot], __log2f(pc) * LN2F);                      \
        atomicAdd(&s_log1m[w][slot], __log2f(1.0f - pc) * LN2F);               \
      }                                                                        \
      packed |= ((unsigned)bc) << (8 * (J));                                   \
      (LW) = bc ? (pibase + (J)) : INVAL;                                      \
    }
    DOPIX(0, p0.x, p1.x, p2.x, p3.x, p4.x, t4.x, labw.x)
    DOPIX(1, p0.y, p1.y, p2.y, p3.y, p4.y, t4.y, labw.y)
    DOPIX(2, p0.z, p1.z, p2.z, p3.z, p4.z, t4.z, labw.z)
    DOPIX(3, p0.w, p1.w, p2.w, p3.w, p4.w, t4.w, labw.w)
#undef DOPIX
    lclsw[li4] = packed;
    *(uint4*)&lab[li4 * 4] = labw;
  }
  __syncthreads();

  // ---- phase 2: tile-local union-find (right + down edges) ----
#pragma unroll
  for (int it = 0; it < 16; ++it) {
    int li = threadIdx.x + it * 256;
    unsigned char c = lcls[li];
    if (!c) continue;
    int tx = li & 63, ty = li >> 6;
    if (tx < 63 && lcls[li + 1] == c)  uniteL(lab, li, li + 1);
    if (ty < 63 && lcls[li + 64] == c) uniteL(lab, li, li + 64);
  }
  __syncthreads();

  // ---- phase 3a: count local roots per class ----
#pragma unroll
  for (int it = 0; it < 16; ++it) {
    int li = threadIdx.x + it * 256;
    unsigned char c = lcls[li];
    if (c && lab[li] == (unsigned)li) atomicAdd(&s_rt[c - 1], 1u);
  }

  // ---- phase 3b: border pass -> compact node ids ----
  // border order: 0-63 top row, 64-127 bottom row, 128-191 left col, 192-255 right col
  {
    int bp = threadIdx.x;            // 0..255
    int tx, ty;
    if (bp < 64)       { ty = 0;        tx = bp; }
    else if (bp < 128) { ty = 63;       tx = bp - 64; }
    else if (bp < 192) { tx = 0;        ty = bp - 128; }
    else               { tx = 63;       ty = bp - 192; }
    int li = ty * 64 + tx;
    unsigned char c = lcls[li];
    unsigned r = 0;
    if (c) {
      r = findRootL(lab, (unsigned)li);
      atomicMin(&s_rootmin[r], (unsigned)bp);
    }
    __syncthreads();
    unsigned sub = c ? s_rootmin[r] : 0u;   // element of the component's border set -> unique
    border[blk * 256 + bp] = (unsigned short)(((unsigned)c << 8) | sub);
  }
  __syncthreads();

  // ---- flush block partials ----
  for (int i = threadIdx.x; i < TB*C_; i += blockDim.x) {
    unsigned c = s_cnt[0][i] + s_cnt[1][i] + s_cnt[2][i] + s_cnt[3][i];
    if (c) atomicAdd(&(&acc->cnt[0][0])[i], c);
    double vp = (double)s_pred[0][i] + s_pred[1][i] + s_pred[2][i] + s_pred[3][i];
    double vl = (double)s_logpc[0][i] + s_logpc[1][i] + s_logpc[2][i] + s_logpc[3][i];
    double vm = (double)s_log1m[0][i] + s_log1m[1][i] + s_log1m[2][i] + s_log1m[3][i];
    if (vp != 0.0)
      atomicAdd((unsigned long long*)&(&acc->f_pred[0][0])[i],
                (unsigned long long)(long long)llrint(vp * FIX));
    if (vl != 0.0)
      atomicAdd((unsigned long long*)&(&acc->f_logpc[0][0])[i],
                (unsigned long long)(long long)llrint(vl * FIX));
    if (vm != 0.0)
      atomicAdd((unsigned long long*)&(&acc->f_log1m[0][0])[i],
                (unsigned long long)(long long)llrint(vm * FIX));
  }
  if (threadIdx.x < 4 && s_rt[threadIdx.x])
    atomicAdd(&acc->ncomp[threadIdx.x], s_rt[threadIdx.x]);
}

// Seam merge on the compact node graph (1.18 MB UF array, L2-resident).
__global__ __launch_bounds__(256) void k_seam(const unsigned short* __restrict__ border,
                                              unsigned* __restrict__ P2,
                                              Acc* __restrict__ acc)
{
  __shared__ unsigned s_sub[4];
  if (threadIdx.x < 4) s_sub[threadIdx.x] = 0u;
  __syncthreads();
  int idx = blockIdx.x * blockDim.x + threadIdx.x;
  if (idx < NB_TOT) {
    int tA, tB, pA, pB;
    if (idx < NB_HALF) {             // down seams: bottom row of tile vs top row of tile below
      int b = idx / SEAMS_PER_IMG;
      int r = idx - b * SEAMS_PER_IMG;
      int seam = r / W_;             // 0..10
      int x = r - seam * W_;         // 0..767
      int tj = x >> 6, k = x & 63;
      tA = (b * TPC + seam) * TPR + tj;
      tB = tA + TPR;
      pA = tA * 256 + 64 + k;        // bottom row pos
      pB = tB * 256 + 0 + k;         // top row pos
    } else {                         // right seams: right col of tile vs left col of tile right
      int i2 = idx - NB_HALF;
      int b = i2 / SEAMS_PER_IMG;
      int r = i2 - b * SEAMS_PER_IMG;
      int seam = r / H_;             // 0..10
      int y = r - seam * H_;         // 0..767
      int ti = y >> 6, k = y & 63;
      tA = (b * TPC + ti) * TPR + seam;
      tB = tA + 1;
      pA = tA * 256 + 192 + k;       // right col pos
      pB = tB * 256 + 128 + k;       // left col pos
    }
    unsigned a16 = border[pA];
    unsigned b16 = border[pB];
    unsigned ca = a16 >> 8, cb = b16 >> 8;
    if (ca && ca == cb) {
      if (uniteG(P2, (unsigned)tA * 256u + (a16 & 255u),
                     (unsigned)tB * 256u + (b16 & 255u)))
        atomicAdd(&s_sub[ca - 1], 1u);
    }
  }
  __syncthreads();
  if (threadIdx.x < 4 && s_sub[threadIdx.x])
    atomicSub(&acc->ncomp[threadIdx.x], s_sub[threadIdx.x]);
}

__global__ void k_final(const Acc* __restrict__ acc, const int* __restrict__ ntcp,
                        float* __restrict__ out)
{
  if (threadIdx.x || blockIdx.x) return;
  int NT = ntcp[0];
  if (NT < 1) NT = 1;
  if (NT > TB) NT = TB;

  double logpc[TB][C_], log1m[TB][C_], spred[TB][C_], cnt[TB][C_];
  unsigned cnti[TB][C_];
  for (int t = 0; t < TB; ++t)
    for (int c = 0; c < C_; ++c) {
      cnti[t][c]  = acc->cnt[t][c];
      cnt[t][c]   = (double)cnti[t][c];
      logpc[t][c] = (double)acc->f_logpc[t][c] / FIX;
      log1m[t][c] = (double)acc->f_log1m[t][c] / FIX;
      spred[t][c] = (double)acc->f_pred[t][c] / FIX;
    }
  unsigned ctot[C_];
  for (int c = 0; c < C_; ++c) {
    unsigned s = 0;
    for (int t = 0; t < TB; ++t) s += cnti[t][c];
    ctot[c] = s;
  }
  unsigned ncomp[C_] = {0, 0, 0, 0, 0};
  for (int v = 1; v < C_; ++v) ncomp[v] = acc->ncomp[v - 1];

  // ph per predicted class: exact f32 replay incl. int32 wrap of n_comp*last_i
  float ph_tab[C_];
  for (int cc = 0; cc < C_; ++cc) {
    float ph = 0.0f;
    int li = 1;
    for (int v = 1; v < C_; ++v) {
      if (ctot[v] > 0) {
        int prod = (int)((unsigned)ncomp[v] * (unsigned)li);
        float sv = (float)prod;
        float inc = ((cc == v) ? 1.0f : 0.0f) + sv;
        ph = ph + inc;
        li = li + (int)ncomp[v] + ((ctot[v] < (unsigned)NPIX) ? 1 : 0);
      }
    }
    ph_tab[cc] = ph;
  }

  const float EPSF = 1e-7f;
  const double L1 = (double)logf(1.0f - EPSF);
  const double M1 = (double)log1pf(-(1.0f - EPSF));
  const double L0 = (double)logf(EPSF);
  const double M0 = (double)log1pf(-EPSF);
  const double N = (double)NPIX;

  double nt0 = 0; for (int c = 0; c < C_; ++c) nt0 += cnt[0][c];
  double np1 = (double)ctot[0];
  double n11 = cnt[0][0];
  double res = -(n11*L1 + (nt0 - n11)*L0 + (np1 - n11)*M1 + (N - nt0 - np1 + n11)*M0) / N
               + 1.0 - (2.0*n11 + 1.0) / (np1 + nt0 + 1.0);

  for (int t = 1; t < NT; ++t) {
    double ntt = 0; long long ntti = 0;
    for (int c = 0; c < C_; ++c) { ntt += cnt[t][c]; ntti += (long long)cnti[t][c]; }
    if (ntti == 0) continue;
    int idx[C_] = {0, 1, 2, 3, 4};
    for (int i = 1; i < C_; ++i)
      for (int j = i; j > 0 && ph_tab[idx[j]] < ph_tab[idx[j-1]]; --j) {
        int tmp = idx[j]; idx[j] = idx[j-1]; idx[j-1] = tmp;
      }
    long long k = (ntti - 1) / 2;
    float med = ph_tab[idx[C_ - 1]];
    long long cum = 0;
    for (int i = 0; i < C_; ++i) {
      cum += (long long)cnti[t][idx[i]];
      if (cum > k) { med = ph_tab[idx[i]]; break; }
    }
    double A = 0, Bt = 0, inter = 0, sum_p = 0, ex = 0, nfg_t = 0, nfg_all = 0;
    for (int c = 1; c < C_; ++c) {
      if (ph_tab[c] == med) {
        A += logpc[t][c];
        inter += spred[t][c];
        nfg_t += cnt[t][c];
        for (int t2 = 0; t2 < TB; ++t2) {
          nfg_all += cnt[t2][c];
          sum_p += spred[t2][c];
          if (t2 != t) Bt += log1m[t2][c];
        }
      } else {
        ex += spred[t][c];
      }
    }
    double bce  = -(A + Bt + (ntt - nfg_t)*L0 + (N - ntt - (nfg_all - nfg_t))*M0) / N;
    double dice = 1.0 - (2.0*inter + 1.0) / (sum_p + ntt + 1.0);
    res += bce + dice + ex / ntt;
  }

  int nun = 0;
  for (int t = 0; t < NT; ++t) {
    long long s = 0;
    for (int c = 0; c < C_; ++c) s += (long long)cnti[t][c];
    if (s) nun++;
  }
  out[0] = (float)(res / (double)(2 * nun + 1));
}

extern "C" void kernel_launch(void* const* d_in, const int* in_sizes, int n_in,
                              void* d_out, int out_size, void* d_ws, size_t ws_size,
                              hipStream_t stream) {
  const float* pred = (const float*)d_in[0];
  const int* tgt = (const int*)d_in[1];
  const int* ntc = (const int*)d_in[2];
  float* out = (float*)d_out;
  char* ws = (char*)d_ws;
  // ws layout: border u16[NTILES*256] (590 KB) | P2 u32[NNODES] (1.18 MB) | Acc  (< 2 MB total)
  unsigned short* border = (unsigned short*)ws;
  unsigned* P2 = (unsigned*)(ws + (size_t)NTILES * 256 * 2);
  Acc* acc = (Acc*)(ws + (size_t)NTILES * 256 * 2 + (size_t)NNODES * 4);

  hipLaunchKernelGGL(k_zero, dim3(1), dim3(256), 0, stream, acc);
  hipLaunchKernelGGL(k_main, dim3(NTILES), dim3(256), 0, stream,
                     (const float4*)pred, (const int4*)tgt, border, P2, acc);
  hipLaunchKernelGGL(k_seam, dim3((NB_TOT + 255) / 256), dim3(256), 0, stream,
                     border, P2, acc);
  hipLaunchKernelGGL(k_final, dim3(1), dim3(1), 0, stream, acc, ntc, out);
}